// Round 3
// baseline (69.791 us; speedup 1.0000x reference)
//
#include <hip/hip_runtime.h>

// Problem constants (match reference)
#define BATCH 256
#define PTS   4096
#define HH    512
#define WW    512

#define ROWS_PER_TILE 32
#define TILES (HH / ROWS_PER_TILE)       // 16 tiles per batch
#define TILE_ELEMS (ROWS_PER_TILE * WW)  // 16384 floats = 64 KB LDS

// Native vector type: __builtin_nontemporal_store requires an
// integer/float/vector-of-such pointer, not HIP's float4 class.
typedef float f32x4 __attribute__((ext_vector_type(4)));

// Tile-gather formulation: each block owns one 32x512 output tile of one
// batch. It zeroes the tile in LDS, scans the batch's valid points,
// accumulates hits with LDS atomics, then writes the tile exactly once
// with non-temporal float4 stores. No global memset, no global atomics:
// HBM traffic = 268 MB output write + ~10 MB input read (write roofline).
__global__ __launch_bounds__(256, 2) void tile_gather_kernel(
        const int* __restrict__ indices,      // [B, P, 2] int32
        const int* __restrict__ num_valid,    // [B] int32
        const float* __restrict__ feats,      // [B, P, 1] f32
        float* __restrict__ out)              // [B, H, W] f32
{
    __shared__ float tile[TILE_ELEMS];

    int blk = blockIdx.x;
    int b = blk >> 4;              // blk / TILES
    int t = blk & (TILES - 1);     // blk % TILES
    int r0 = t * ROWS_PER_TILE;
    int tidx = threadIdx.x;

    // Zero the LDS tile (64 floats per thread, conflict-free)
    #pragma unroll
    for (int i = tidx; i < TILE_ELEMS; i += 256)
        tile[i] = 0.0f;

    int nv = num_valid[b];         // block-uniform
    __syncthreads();

    const int2* idx2 = reinterpret_cast<const int2*>(indices) + (size_t)b * PTS;
    const float* fb  = feats + (size_t)b * PTS;

    // Scan only the valid prefix of this batch's points (L2-resident:
    // 32 KB indices/batch read by 16 tile blocks).
    for (int p = tidx; p < nv; p += 256) {
        int2 ij = idx2[p];         // coalesced 8B/lane
        int r = ij.x - r0;
        if ((unsigned)r < ROWS_PER_TILE) {
            atomicAdd(&tile[r * WW + ij.y], fb[p]);   // LDS atomic, ~128 hits/block
        }
    }
    __syncthreads();

    // Write the tile once: 16384 floats = 4096 float4, 16 per thread,
    // non-temporal (output is never re-read).
    float* ob = out + (size_t)b * (HH * WW) + (size_t)r0 * WW;
    const f32x4* src = reinterpret_cast<const f32x4*>(tile);
    f32x4* dst = reinterpret_cast<f32x4*>(ob);
    #pragma unroll
    for (int i = tidx; i < TILE_ELEMS / 4; i += 256)
        __builtin_nontemporal_store(src[i], dst + i);
}

extern "C" void kernel_launch(void* const* d_in, const int* in_sizes, int n_in,
                              void* d_out, int out_size, void* d_ws, size_t ws_size,
                              hipStream_t stream) {
    const int*   indices   = (const int*)d_in[0];
    const int*   num_valid = (const int*)d_in[1];
    const float* feats     = (const float*)d_in[2];
    float*       out       = (float*)d_out;

    // Every output element is written exactly once by its owning tile
    // block, so no memset is needed.
    tile_gather_kernel<<<BATCH * TILES, 256, 0, stream>>>(indices, num_valid, feats, out);
}

// Round 4
// 50.881 us; speedup vs baseline: 1.3716x; 1.3716x over previous
//
#include <hip/hip_runtime.h>

// Problem constants (match reference)
#define BATCH 256
#define PTS   4096
#define HH    512
#define WW    512

#define ROWS_PER_TILE 16
#define TILES (HH / ROWS_PER_TILE)       // 32 tiles per batch
#define TILE_ELEMS (ROWS_PER_TILE * WW)  // 8192 floats = 32 KB LDS

// Native vector type: __builtin_nontemporal_store requires an
// integer/float/vector-of-such pointer, not HIP's float4 class.
typedef float f32x4 __attribute__((ext_vector_type(4)));

// Tile-gather: each block owns one 16x512 output tile of one batch.
// 32 KB LDS -> 5 blocks/CU resident, so scans overlap other blocks'
// write bursts. Output written exactly once, non-temporal; no memset,
// no global atomics. HBM traffic ~= 268 MB write + ~12 MB read.
__global__ __launch_bounds__(256) void tile_gather_kernel(
        const int* __restrict__ indices,      // [B, P, 2] int32
        const int* __restrict__ num_valid,    // [B] int32
        const float* __restrict__ feats,      // [B, P, 1] f32
        float* __restrict__ out)              // [B, H, W] f32
{
    __shared__ float tile[TILE_ELEMS];

    // XCD-aware remap: hardware round-robins blockIdx across the 8 XCDs.
    // Map launch index so each XCD gets 32 whole batches (all 32 tiles):
    // the batch's 32 KB index list + 16 KB feats stay in ONE L2.
    int i = blockIdx.x;                       // [0, 8192)
    int xcd  = i & 7;
    int slot = i >> 3;                        // [0, 1024)
    int b = xcd * (BATCH / 8) + (slot >> 5);  // 32 batches per XCD
    int t = slot & (TILES - 1);
    int r0 = t * ROWS_PER_TILE;
    int tidx = threadIdx.x;

    // Zero the LDS tile, vectorized (ds_write_b128): 8 stores/thread.
    f32x4* tile4 = reinterpret_cast<f32x4*>(tile);
    #pragma unroll
    for (int k = tidx; k < TILE_ELEMS / 4; k += 256)
        tile4[k] = (f32x4){0.f, 0.f, 0.f, 0.f};

    int nv = num_valid[b];                    // block-uniform
    __syncthreads();

    // Scan the valid prefix, 2 points per int4 load (L2-resident).
    const int4* idx4 = reinterpret_cast<const int4*>(indices) + (size_t)b * (PTS / 2);
    const float* fb  = feats + (size_t)b * PTS;

    int n4 = (nv + 1) >> 1;                   // pairs to visit
    for (int q = tidx; q < n4; q += 256) {
        int4 two = idx4[q];                   // points 2q (x,y) and 2q+1 (z,w)
        int r0a = two.x - r0;
        if ((unsigned)r0a < ROWS_PER_TILE)
            atomicAdd(&tile[r0a * WW + two.y], fb[2 * q]);
        int p1 = 2 * q + 1;
        int r1a = two.z - r0;
        if (p1 < nv && (unsigned)r1a < ROWS_PER_TILE)
            atomicAdd(&tile[r1a * WW + two.w], fb[p1]);
    }
    __syncthreads();

    // Write the tile exactly once: 2048 float4 stores, 8 per thread,
    // non-temporal (output never re-read).
    float* ob = out + (size_t)b * (HH * WW) + (size_t)r0 * WW;
    f32x4* dst = reinterpret_cast<f32x4*>(ob);
    #pragma unroll
    for (int k = tidx; k < TILE_ELEMS / 4; k += 256)
        __builtin_nontemporal_store(tile4[k], dst + k);
}

extern "C" void kernel_launch(void* const* d_in, const int* in_sizes, int n_in,
                              void* d_out, int out_size, void* d_ws, size_t ws_size,
                              hipStream_t stream) {
    const int*   indices   = (const int*)d_in[0];
    const int*   num_valid = (const int*)d_in[1];
    const float* feats     = (const float*)d_in[2];
    float*       out       = (float*)d_out;

    tile_gather_kernel<<<BATCH * TILES, 256, 0, stream>>>(indices, num_valid, feats, out);
}